// Round 11
// baseline (78.168 us; speedup 1.0000x reference)
//
#include <hip/hip_runtime.h>
#include <math.h>

#define BB 4
#define TT 1024
#define EE 512
#define HH 8
#define DD 64
#define BT (BB * TT)   // 4096

typedef _Float16 f16;
typedef __attribute__((ext_vector_type(8))) _Float16 f16x8;
typedef __attribute__((ext_vector_type(4))) float f32x4;

// ---------------------------------------------------------------------------
// Prep: y=0..3 weight planes (transposed f16), y=4/5 split q/kv into hi+lo
// f16 planes [BT][512]. Grid (1024, 6).
// ---------------------------------------------------------------------------
__global__ __launch_bounds__(256) void prep_k(
    const float* __restrict__ q, const float* __restrict__ kv,
    const float* __restrict__ Wq, const float* __restrict__ Wk,
    const float* __restrict__ Wv, const float* __restrict__ Wo,
    f16* __restrict__ wqh, f16* __restrict__ wql,
    f16* __restrict__ wkh, f16* __restrict__ wkl,
    f16* __restrict__ wvh, f16* __restrict__ woh,
    f16* __restrict__ qAhi, f16* __restrict__ qAlo,
    f16* __restrict__ kvAhi, f16* __restrict__ kvAlo) {
    const int t = threadIdx.x;
    const int y = blockIdx.y;
    if (y < 4) {
        int idx = blockIdx.x * 256 + t;        // 512*512 elems
        int k = idx & (EE - 1);
        int n = idx >> 9;
        if (y == 0) {
            float v = Wq[k * EE + n] * 512.0f; // fold dk*D scale (exact pow2)
            f16 hi = (f16)v;
            wqh[n * EE + k] = hi;
            wql[n * EE + k] = (f16)(v - (float)hi);
        } else if (y == 1) {
            int d = n >> 3, h = n & 7;
            int sn = (((DD - d) & (DD - 1)) << 3) | h;  // K'[.,d]=K[.,(D-d)%D]
            float v = Wk[k * EE + sn];
            f16 hi = (f16)v;
            wkh[n * EE + k] = hi;
            wkl[n * EE + k] = (f16)(v - (float)hi);
        } else if (y == 2) {
            wvh[n * EE + k] = (f16)Wv[k * EE + n];
        } else {
            woh[n * EE + k] = (f16)Wo[k * EE + n];
        }
    } else {
        const float* src = (y == 4) ? q : kv;
        f16* dh = (y == 4) ? qAhi : kvAhi;
        f16* dl = (y == 4) ? qAlo : kvAlo;
        int base = (blockIdx.x * 256 + t) * 8;
        float4 a = *(const float4*)&src[base];
        float4 c = *(const float4*)&src[base + 4];
        float xs[8] = {a.x, a.y, a.z, a.w, c.x, c.y, c.z, c.w};
        f16x8 hi, lo;
#pragma unroll
        for (int e = 0; e < 8; ++e) {
            f16 hh = (f16)xs[e];
            hi[e] = hh;
            lo[e] = (f16)(xs[e] - (float)hh);
        }
        *(f16x8*)&dh[base] = hi;
        *(f16x8*)&dl[base] = lo;
    }
}

// ---------------------------------------------------------------------------
// Fused projection. Grid (BT/128, EE/64, 2), block 256 (4 waves).
// z=0: Q -> head planes (qhi,qlo). z=1: K' -> FRAGMENT-PACKED planes
// kthi/ktlo [h][b][kt64][kt][kf][lane][8], V -> packed vP.
// Tile 128x64, BK=32, dbuf LDS + 2-deep reg prefetch.
// ---------------------------------------------------------------------------
__global__ __launch_bounds__(256) void proj_k(
    const f16* __restrict__ qAhi, const f16* __restrict__ qAlo,
    const f16* __restrict__ kvAhi, const f16* __restrict__ kvAlo,
    const f16* __restrict__ wqh, const f16* __restrict__ wql,
    const f16* __restrict__ wkh, const f16* __restrict__ wkl,
    const f16* __restrict__ wvh,
    f16* __restrict__ qhi, f16* __restrict__ qlo,
    f16* __restrict__ kthi, f16* __restrict__ ktlo, f16* __restrict__ vP) {
    __shared__ __align__(16) f16 Ah_s[2][128][40];
    __shared__ __align__(16) f16 Al_s[2][128][40];
    __shared__ __align__(16) f16 Wh_s[2][64][40];
    __shared__ __align__(16) f16 Wl_s[2][64][40];
    __shared__ __align__(16) f16 Wv_s[2][64][40];
    f16 (*Ep)[136] = reinterpret_cast<f16(*)[136]>(&Ah_s[0][0][0]);

    const int t = threadIdx.x;
    const int w = t >> 6, l = t & 63;
    const int wm = w >> 1, wn = w & 1;
    const int fr = l & 15, fc = l >> 4;
    const int m0b = blockIdx.x * 128;
    const int n0b = blockIdx.y * 64;
    const int z   = blockIdx.z;
    const int ar = t >> 1, ak = t & 1;
    const int wr = t >> 2, wc = t & 3;

    const f16* AH = z ? kvAhi : qAhi;
    const f16* AL = z ? kvAlo : qAlo;
    const f16* WH = z ? wkh : wqh;
    const f16* WL = z ? wkl : wql;

    f32x4 accK[4][2], accV[4][2];
#pragma unroll
    for (int i = 0; i < 4; ++i)
#pragma unroll
        for (int j = 0; j < 2; ++j) {
            accK[i][j] = f32x4{0.f, 0.f, 0.f, 0.f};
            accV[i][j] = f32x4{0.f, 0.f, 0.f, 0.f};
        }

    f16x8 ahA[2], alA[2], whA, wlA, wvA;
    f16x8 ahB[2], alB[2], whB, wlB, wvB;

    auto loadSet = [&](int k0, f16x8 (&ah)[2], f16x8 (&al)[2],
                       f16x8& wh, f16x8& wl, f16x8& wv) {
        size_t aoff = (size_t)(m0b + ar) * EE + k0 + ak * 16;
        ah[0] = *(const f16x8*)&AH[aoff];
        ah[1] = *(const f16x8*)&AH[aoff + 8];
        al[0] = *(const f16x8*)&AL[aoff];
        al[1] = *(const f16x8*)&AL[aoff + 8];
        size_t woff = (size_t)(n0b + wr) * EE + k0 + wc * 8;
        wh = *(const f16x8*)&WH[woff];
        wl = *(const f16x8*)&WL[woff];
        if (z) wv = *(const f16x8*)&wvh[woff];
    };
    auto stageSet = [&](int bf, f16x8 (&ah)[2], f16x8 (&al)[2],
                        f16x8& wh, f16x8& wl, f16x8& wv) {
        *(f16x8*)&Ah_s[bf][ar][ak * 16]     = ah[0];
        *(f16x8*)&Ah_s[bf][ar][ak * 16 + 8] = ah[1];
        *(f16x8*)&Al_s[bf][ar][ak * 16]     = al[0];
        *(f16x8*)&Al_s[bf][ar][ak * 16 + 8] = al[1];
        *(f16x8*)&Wh_s[bf][wr][wc * 8] = wh;
        *(f16x8*)&Wl_s[bf][wr][wc * 8] = wl;
        if (z) *(f16x8*)&Wv_s[bf][wr][wc * 8] = wv;
    };
    auto comp = [&](int bf) {
        f16x8 Ahf[4], Alf[4], Bh[2], Bl[2], Bv[2];
#pragma unroll
        for (int mi = 0; mi < 4; ++mi) {
            Ahf[mi] = *(const f16x8*)&Ah_s[bf][wm * 64 + mi * 16 + fr][fc * 8];
            Alf[mi] = *(const f16x8*)&Al_s[bf][wm * 64 + mi * 16 + fr][fc * 8];
        }
#pragma unroll
        for (int nj = 0; nj < 2; ++nj) {
            Bh[nj] = *(const f16x8*)&Wh_s[bf][wn * 32 + nj * 16 + fr][fc * 8];
            Bl[nj] = *(const f16x8*)&Wl_s[bf][wn * 32 + nj * 16 + fr][fc * 8];
            if (z) Bv[nj] = *(const f16x8*)&Wv_s[bf][wn * 32 + nj * 16 + fr][fc * 8];
        }
        __builtin_amdgcn_s_setprio(1);
#pragma unroll
        for (int mi = 0; mi < 4; ++mi)
#pragma unroll
            for (int nj = 0; nj < 2; ++nj) {
                accK[mi][nj] = __builtin_amdgcn_mfma_f32_16x16x32_f16(
                    Ahf[mi], Bh[nj], accK[mi][nj], 0, 0, 0);
                accK[mi][nj] = __builtin_amdgcn_mfma_f32_16x16x32_f16(
                    Ahf[mi], Bl[nj], accK[mi][nj], 0, 0, 0);
                accK[mi][nj] = __builtin_amdgcn_mfma_f32_16x16x32_f16(
                    Alf[mi], Bh[nj], accK[mi][nj], 0, 0, 0);
                if (z)
                    accV[mi][nj] = __builtin_amdgcn_mfma_f32_16x16x32_f16(
                        Ahf[mi], Bv[nj], accV[mi][nj], 0, 0, 0);
            }
        __builtin_amdgcn_s_setprio(0);
    };

    loadSet(0, ahA, alA, whA, wlA, wvA);
    stageSet(0, ahA, alA, whA, wlA, wvA);
    loadSet(32, ahA, alA, whA, wlA, wvA);
    loadSet(64, ahB, alB, whB, wlB, wvB);
    __syncthreads();

    for (int ks = 0; ks < 16; ks += 2) {
        comp(0);
        stageSet(1, ahA, alA, whA, wlA, wvA);
        if (ks + 3 < 16) loadSet((ks + 3) * 32, ahA, alA, whA, wlA, wvA);
        __syncthreads();
        comp(1);
        if (ks + 2 < 16) stageSet(0, ahB, alB, whB, wlB, wvB);
        if (ks + 4 < 16) loadSet((ks + 4) * 32, ahB, alB, whB, wlB, wvB);
        __syncthreads();
    }

    // ---- epilogue (Ep aliases dead LDS) ----
    const int d0  = n0b >> 3;            // first head-dim of this n-slice
    const int kfc = d0 >> 5;             // K-frag kf
    const int lg2 = (d0 >> 3) & 3;       // K-frag lane group
#pragma unroll
    for (int mi = 0; mi < 4; ++mi)
#pragma unroll
        for (int nj = 0; nj < 2; ++nj)
#pragma unroll
            for (int r = 0; r < 4; ++r)
                Ep[wn * 32 + nj * 16 + fr][wm * 64 + mi * 16 + fc * 4 + r] =
                    (f16)accK[mi][nj][r];
    __syncthreads();
#pragma unroll
    for (int i = 0; i < 4; ++i) {
        int task = t * 4 + i;            // (mr 0..127, h 0..7)
        int mr = task >> 3, h = task & 7;
        f16x8 v;
#pragma unroll
        for (int d = 0; d < 8; ++d) v[d] = Ep[8 * d + h][mr];
        if (z == 0) {
            *(f16x8*)&qhi[((size_t)h * BT + m0b + mr) * DD + d0] = v;
        } else {
            int mg = m0b + mr;
            int bb = mg >> 10, key = mg & 1023;
            size_t off = ((((((size_t)h * BB + bb) * 16 + (key >> 6)) * 4 +
                            ((key >> 4) & 3)) * 2 + kfc) * 64 +
                          lg2 * 16 + (key & 15)) * 8;
            *(f16x8*)&kthi[off] = v;
        }
    }
    __syncthreads();
#pragma unroll
    for (int mi = 0; mi < 4; ++mi)
#pragma unroll
        for (int nj = 0; nj < 2; ++nj)
#pragma unroll
            for (int r = 0; r < 4; ++r) {
                float x = accK[mi][nj][r];
                f16 hh = (f16)x;
                Ep[wn * 32 + nj * 16 + fr][wm * 64 + mi * 16 + fc * 4 + r] =
                    (f16)(x - (float)hh);
            }
    __syncthreads();
#pragma unroll
    for (int i = 0; i < 4; ++i) {
        int task = t * 4 + i;
        int mr = task >> 3, h = task & 7;
        f16x8 v;
#pragma unroll
        for (int d = 0; d < 8; ++d) v[d] = Ep[8 * d + h][mr];
        if (z == 0) {
            *(f16x8*)&qlo[((size_t)h * BT + m0b + mr) * DD + d0] = v;
        } else {
            int mg = m0b + mr;
            int bb = mg >> 10, key = mg & 1023;
            size_t off = ((((((size_t)h * BB + bb) * 16 + (key >> 6)) * 4 +
                            ((key >> 4) & 3)) * 2 + kfc) * 64 +
                          lg2 * 16 + (key & 15)) * 8;
            *(f16x8*)&ktlo[off] = v;
        }
    }
    if (z) {
        __syncthreads();
#pragma unroll
        for (int mi = 0; mi < 4; ++mi)
#pragma unroll
            for (int nj = 0; nj < 2; ++nj)
#pragma unroll
                for (int r = 0; r < 4; ++r)
                    Ep[wn * 32 + nj * 16 + fr][wm * 64 + mi * 16 + fc * 4 + r] =
                        (f16)accV[mi][nj][r];
        __syncthreads();
        // V fragment-packed store: vP[h][tile][kf][dvt][lane][8]
#pragma unroll
        for (int i = 0; i < 4; ++i) {
            int task = t * 4 + i;           // (nn 0..63, mg 0..15)
            int mg = task & 15, nn = task >> 4;
            int h = nn & 7, dl = nn >> 3;
            int d = d0 + dl;
            int koff = m0b + mg * 8;
            int tile = koff >> 6;
            int kf   = (koff >> 5) & 1;
            int lgv  = (koff >> 3) & 3;
            int dvt  = d >> 4, lqd = d & 15;
            f16x8 v = *(const f16x8*)&Ep[nn][mg * 8];
            size_t off = (((((size_t)h * 64 + tile) * 2 + kf) * 4 + dvt) * 64 +
                          lgv * 16 + lqd) * 8;
            *(f16x8*)&vP[off] = v;
        }
    }
}

// ---------------------------------------------------------------------------
// Output GEMM: out = ctx(f16) @ Wo (f16) -> fp32. Tile 64x64, BK=64.
// ---------------------------------------------------------------------------
__global__ __launch_bounds__(256) void outmm_k(const f16* __restrict__ Af,
                                               const f16* __restrict__ WThi,
                                               float* __restrict__ out) {
    __shared__ __align__(16) f16 Ah_s[2][64][72];
    __shared__ __align__(16) f16 Wh_s[2][64][72];

    const int t = threadIdx.x;
    const int w = t >> 6, l = t & 63;
    const int wm = w >> 1, wn = w & 1;
    const int fr = l & 15, fc = l >> 4;
    const int m0b = blockIdx.x * 64;
    const int n0b = blockIdx.y * 64;
    const int sr = t >> 2, sch = t & 3;

    f32x4 acc[2][2];
#pragma unroll
    for (int i = 0; i < 2; ++i)
#pragma unroll
        for (int j = 0; j < 2; ++j) acc[i][j] = f32x4{0.f, 0.f, 0.f, 0.f};

    f16x8 af[2], wf[2];
    auto loadAB = [&](int k0) {
#pragma unroll
        for (int i = 0; i < 2; ++i) {
            af[i] = *(const f16x8*)&Af[(size_t)(m0b + sr) * EE + k0 + sch * 16 + i * 8];
            wf[i] = *(const f16x8*)&WThi[(size_t)(n0b + sr) * EE + k0 + sch * 16 + i * 8];
        }
    };
    auto stage = [&](int bf) {
#pragma unroll
        for (int i = 0; i < 2; ++i) {
            *(f16x8*)&Ah_s[bf][sr][sch * 16 + i * 8] = af[i];
            *(f16x8*)&Wh_s[bf][sr][sch * 16 + i * 8] = wf[i];
        }
    };

    loadAB(0);
    stage(0);
    __syncthreads();
    int cur = 0;
    for (int ks = 0; ks < 8; ++ks) {
        if (ks < 7) loadAB((ks + 1) * 64);
        f16x8 Ahf[2][2], Bhf[2][2];
#pragma unroll
        for (int mi = 0; mi < 2; ++mi)
#pragma unroll
            for (int kb = 0; kb < 2; ++kb)
                Ahf[mi][kb] =
                    *(const f16x8*)&Ah_s[cur][wm * 32 + mi * 16 + fr][kb * 32 + fc * 8];
#pragma unroll
        for (int nj = 0; nj < 2; ++nj)
#pragma unroll
            for (int kb = 0; kb < 2; ++kb)
                Bhf[nj][kb] =
                    *(const f16x8*)&Wh_s[cur][wn * 32 + nj * 16 + fr][kb * 32 + fc * 8];
        __builtin_amdgcn_s_setprio(1);
#pragma unroll
        for (int mi = 0; mi < 2; ++mi)
#pragma unroll
            for (int nj = 0; nj < 2; ++nj)
#pragma unroll
                for (int kb = 0; kb < 2; ++kb)
                    acc[mi][nj] = __builtin_amdgcn_mfma_f32_16x16x32_f16(
                        Ahf[mi][kb], Bhf[nj][kb], acc[mi][nj], 0, 0, 0);
        __builtin_amdgcn_s_setprio(0);
        if (ks < 7) stage(cur ^ 1);
        __syncthreads();
        cur ^= 1;
    }

#pragma unroll
    for (int mi = 0; mi < 2; ++mi)
#pragma unroll
        for (int nj = 0; nj < 2; ++nj)
#pragma unroll
            for (int r = 0; r < 4; ++r)
                out[(size_t)(m0b + wm * 32 + mi * 16 + fc * 4 + r) * EE +
                    n0b + wn * 32 + nj * 16 + fr] = acc[mi][nj][r];
}

// ---------------------------------------------------------------------------
// Barrier-free MFMA flash attention. K and V fragments loaded directly from
// fragment-packed global planes (coalesced 1KB L2 loads) into registers —
// no K LDS, no staging, ZERO __syncthreads. P via per-wave LDS buffer.
// K-frags pipelined one kt-group ahead (A/B reg sets); V one tile ahead.
// defer-max, XCD-swizzled grid (512).
// ---------------------------------------------------------------------------
__global__ __launch_bounds__(256) void attn_mfma_k(const f16* __restrict__ qhiP,
    const f16* __restrict__ qloP, const f16* __restrict__ kthiP,
    const f16* __restrict__ ktloP, const f16* __restrict__ vP,
    f16* __restrict__ ctx) {
    __shared__ __align__(16) f16 Pl[4][16][88];    // per-wave P[q][key]

    const int bid = blockIdx.x;                 // 0..511
    const int swz = (bid & 7) * 64 + (bid >> 3);
    const int bx = swz & 15;
    const int h  = (swz >> 4) & 7;
    const int b  = swz >> 7;

    const int t  = threadIdx.x;
    const int w  = t >> 6;
    const int l  = t & 63;
    const int lg = l >> 4;
    const int lq = l & 15;
    const int q0 = bx * 64 + w * 16;
    const size_t plane = ((size_t)h * BT + (size_t)b * TT) * DD;

    f16x8 Qhi[2], Qlo[2];
#pragma unroll
    for (int kf = 0; kf < 2; ++kf) {
        size_t qo = plane + (size_t)(q0 + lq) * DD + kf * 32 + lg * 8;
        Qhi[kf] = *(const f16x8*)&qhiP[qo];
        Qlo[kf] = *(const f16x8*)&qloP[qo];
    }

    f32x4 Oacc[4];
#pragma unroll
    for (int i = 0; i < 4; ++i) Oacc[i] = f32x4{0.f, 0.f, 0.f, 0.f};
    float m = -1e30f, lsum = 0.f;

    // packed-K bases for this (h,b): [kt64][kt][kf][lane][8]
    const f16* khb = kthiP + (((size_t)h * BB + b) << 16);
    const f16* klb = ktloP + (((size_t)h * BB + b) << 16);

    f16x8 kA[4], kB[4];    // [0]=hi kf0, [1]=hi kf1, [2]=lo kf0, [3]=lo kf1
    auto LK = [&](int kt64, int kt, f16x8 (&s)[4]) {
        size_t o = ((size_t)kt64 * 4 + kt) * 1024 + l * 8;
        s[0] = *(const f16x8*)&khb[o];
        s[1] = *(const f16x8*)&khb[o + 512];
        s[2] = *(const f16x8*)&klb[o];
        s[3] = *(const f16x8*)&klb[o + 512];
    };
    auto QK1 = [&](const f16x8 (&s)[4]) -> f32x4 {
        f32x4 c = f32x4{0.f, 0.f, 0.f, 0.f};
        __builtin_amdgcn_s_setprio(1);
        c = __builtin_amdgcn_mfma_f32_16x16x32_f16(s[0], Qhi[0], c, 0, 0, 0);
        c = __builtin_amdgcn_mfma_f32_16x16x32_f16(s[0], Qlo[0], c, 0, 0, 0);
        c = __builtin_amdgcn_mfma_f32_16x16x32_f16(s[2], Qhi[0], c, 0, 0, 0);
        c = __builtin_amdgcn_mfma_f32_16x16x32_f16(s[1], Qhi[1], c, 0, 0, 0);
        c = __builtin_amdgcn_mfma_f32_16x16x32_f16(s[1], Qlo[1], c, 0, 0, 0);
        c = __builtin_amdgcn_mfma_f32_16x16x32_f16(s[3], Qhi[1], c, 0, 0, 0);
        __builtin_amdgcn_s_setprio(0);
        return c;
    };

    f16x8 bvA[2][4], bvB[2][4];
    auto loadBV = [&](int tile, f16x8 (&bv)[2][4]) {
        const f16* tb = vP + ((size_t)h * 64 + b * 16 + tile) * 4096;
#pragma unroll
        for (int kf = 0; kf < 2; ++kf)
#pragma unroll
            for (int dvt = 0; dvt < 4; ++dvt)
                bv[kf][dvt] = *(const f16x8*)&tb[((kf * 4 + dvt) * 64 + l) * 8];
    };

    auto SMPV = [&](const f32x4 (&Sc)[4], const f16x8 (&bv)[2][4]) {
        float sv[16];
#pragma unroll
        for (int kt = 0; kt < 4; ++kt)
#pragma unroll
            for (int r = 0; r < 4; ++r) sv[kt * 4 + r] = Sc[kt][r];
        float tm = sv[0];
#pragma unroll
        for (int i = 1; i < 16; ++i) tm = fmaxf(tm, sv[i]);
        tm = fmaxf(tm, __shfl_xor(tm, 16));
        tm = fmaxf(tm, __shfl_xor(tm, 32));

        bool skip = __all(tm <= m + 8.0f);
        float Mn = m, corr = 1.0f;
        if (!skip) {
            Mn = fmaxf(m, tm);
            corr = __expf(m - Mn);
        }
        float ps = 0.f;
        f16 ph[16];
#pragma unroll
        for (int i = 0; i < 16; ++i) {
            float p = __expf(sv[i] - Mn);
            ps += p;
            ph[i] = (f16)p;
        }
        ps += __shfl_xor(ps, 16);
        ps += __shfl_xor(ps, 32);
        if (skip) {
            lsum += ps;
        } else {
            lsum = lsum * corr + ps;
            m = Mn;
        }

#pragma unroll
        for (int kt = 0; kt < 4; ++kt)
#pragma unroll
            for (int rp = 0; rp < 4; rp += 2) {
                union { f16 h; unsigned short u; } u0, u1;
                u0.h = ph[kt * 4 + rp]; u1.h = ph[kt * 4 + rp + 1];
                unsigned int pk = ((unsigned int)u1.u << 16) | u0.u;
                *(unsigned int*)&Pl[w][lq][kt * 16 + lg * 4 + rp] = pk;
            }

        if (!skip) {
            float cq[4];
#pragma unroll
            for (int r = 0; r < 4; ++r) cq[r] = __shfl(corr, lg * 4 + r);
#pragma unroll
            for (int dvt = 0; dvt < 4; ++dvt)
#pragma unroll
                for (int r = 0; r < 4; ++r) Oacc[dvt][r] *= cq[r];
        }

        __builtin_amdgcn_s_setprio(1);
#pragma unroll
        for (int kf = 0; kf < 2; ++kf) {
            f16x8 pa = *(const f16x8*)&Pl[w][lq][kf * 32 + lg * 8];
#pragma unroll
            for (int dvt = 0; dvt < 4; ++dvt)
                Oacc[dvt] = __builtin_amdgcn_mfma_f32_16x16x32_f16(
                    pa, bv[kf][dvt], Oacc[dvt], 0, 0, 0);
        }
        __builtin_amdgcn_s_setprio(0);
    };

    // ---- prologue ----
    LK(0, 0, kA);
    loadBV(0, bvA);
    f32x4 Sc[4];

    for (int tile = 0; tile < 16; tile += 2) {
        // even tile (V in bvA)
        LK(tile, 1, kB);      Sc[0] = QK1(kA);
        LK(tile, 2, kA);      Sc[1] = QK1(kB);
        LK(tile, 3, kB);      Sc[2] = QK1(kA);
        LK(tile + 1, 0, kA);  Sc[3] = QK1(kB);
        loadBV(tile + 1, bvB);
        SMPV(Sc, bvA);
        // odd tile (V in bvB)
        LK(tile + 1, 1, kB);  Sc[0] = QK1(kA);
        LK(tile + 1, 2, kA);  Sc[1] = QK1(kB);
        LK(tile + 1, 3, kB);  Sc[2] = QK1(kA);
        if (tile + 2 < 16) LK(tile + 2, 0, kA);
        Sc[3] = QK1(kB);
        if (tile + 2 < 16) loadBV(tile + 2, bvA);
        SMPV(Sc, bvB);
    }

    float linv = 1.0f / lsum;
    float lq4[4];
#pragma unroll
    for (int r = 0; r < 4; ++r) lq4[r] = __shfl(linv, lg * 4 + r);
#pragma unroll
    for (int r = 0; r < 4; ++r) {
        f16* crow = ctx + (size_t)(b * TT + q0 + lg * 4 + r) * EE + h * DD;
#pragma unroll
        for (int dvt = 0; dvt < 4; ++dvt)
            crow[dvt * 16 + lq] = (f16)(Oacc[dvt][r] * lq4[r]);
    }
}

// ---------------------------------------------------------------------------
extern "C" void kernel_launch(void* const* d_in, const int* in_sizes, int n_in,
                              void* d_out, int out_size, void* d_ws, size_t ws_size,
                              hipStream_t stream) {
    const float* q  = (const float*)d_in[0];
    const float* kv = (const float*)d_in[1];
    const float* Wq = (const float*)d_in[2];
    const float* Wk = (const float*)d_in[3];
    const float* Wv = (const float*)d_in[4];
    const float* Wo = (const float*)d_in[5];
    float* out = (float*)d_out;

    f16* ws = (f16*)d_ws;
    const size_t PL  = (size_t)HH * BT * DD;   // 2,097,152 f16 per plane
    const size_t WPL = (size_t)EE * EE;
    f16* qhi   = ws + 0 * PL;
    f16* qlo   = ws + 1 * PL;
    f16* kthi  = ws + 2 * PL;      // packed K frags [H][B][16][4][2][64][8]
    f16* ktlo  = ws + 3 * PL;
    f16* vPck  = ws + 4 * PL;      // packed V frags [H][64][2][4][64][8]
    f16* ctx   = ws + 5 * PL;      // [BT][512]
    f16* qAhi  = ws + 6 * PL;
    f16* qAlo  = ws + 7 * PL;
    f16* kvAhi = ws + 8 * PL;
    f16* kvAlo = ws + 9 * PL;
    f16* wqh = ws + 10 * PL;
    f16* wql = wqh + 1 * WPL;
    f16* wkh = wqh + 2 * WPL;
    f16* wkl = wqh + 3 * WPL;
    f16* wvh = wqh + 4 * WPL;
    f16* woh = wqh + 5 * WPL;

    prep_k<<<dim3(1024, 6), dim3(256), 0, stream>>>(
        q, kv, Wq, Wk, Wv, Wo, wqh, wql, wkh, wkl, wvh, woh,
        qAhi, qAlo, kvAhi, kvAlo);

    proj_k<<<dim3(BT / 128, EE / 64, 2), dim3(256), 0, stream>>>(
        qAhi, qAlo, kvAhi, kvAlo, wqh, wql, wkh, wkl, wvh,
        qhi, qlo, kthi, ktlo, vPck);

    attn_mfma_k<<<dim3(512), dim3(256), 0, stream>>>(
        qhi, qlo, kthi, ktlo, vPck, ctx);

    outmm_k<<<dim3(BT / 64, EE / 64), dim3(256), 0, stream>>>(ctx, woh, out);
}

// Round 12
// 77.306 us; speedup vs baseline: 1.0112x; 1.0112x over previous
//
#include <hip/hip_runtime.h>
#include <math.h>

#define BB 4
#define TT 1024
#define EE 512
#define HH 8
#define DD 64
#define BT (BB * TT)   // 4096

typedef _Float16 f16;
typedef __attribute__((ext_vector_type(8))) _Float16 f16x8;
typedef __attribute__((ext_vector_type(4))) float f32x4;

// direct global->LDS DMA, 16B per lane. LDS dest = wave-uniform base + lane*16.
__device__ __forceinline__ void dma16(const f16* g, char* l) {
    __builtin_amdgcn_global_load_lds(
        (const __attribute__((address_space(1))) void*)g,
        (__attribute__((address_space(3))) void*)l, 16, 0, 0);
}

// ---------------------------------------------------------------------------
// Prep: y=0..3 weight planes (transposed f16), y=4/5 split q/kv into hi+lo
// f16 planes [BT][512]. Grid (1024, 6).
// ---------------------------------------------------------------------------
__global__ __launch_bounds__(256) void prep_k(
    const float* __restrict__ q, const float* __restrict__ kv,
    const float* __restrict__ Wq, const float* __restrict__ Wk,
    const float* __restrict__ Wv, const float* __restrict__ Wo,
    f16* __restrict__ wqh, f16* __restrict__ wql,
    f16* __restrict__ wkh, f16* __restrict__ wkl,
    f16* __restrict__ wvh, f16* __restrict__ woh,
    f16* __restrict__ qAhi, f16* __restrict__ qAlo,
    f16* __restrict__ kvAhi, f16* __restrict__ kvAlo) {
    const int t = threadIdx.x;
    const int y = blockIdx.y;
    if (y < 4) {
        int idx = blockIdx.x * 256 + t;        // 512*512 elems
        int k = idx & (EE - 1);
        int n = idx >> 9;
        if (y == 0) {
            float v = Wq[k * EE + n] * 512.0f; // fold dk*D scale (exact pow2)
            f16 hi = (f16)v;
            wqh[n * EE + k] = hi;
            wql[n * EE + k] = (f16)(v - (float)hi);
        } else if (y == 1) {
            int d = n >> 3, h = n & 7;
            int sn = (((DD - d) & (DD - 1)) << 3) | h;  // K'[.,d]=K[.,(D-d)%D]
            float v = Wk[k * EE + sn];
            f16 hi = (f16)v;
            wkh[n * EE + k] = hi;
            wkl[n * EE + k] = (f16)(v - (float)hi);
        } else if (y == 2) {
            wvh[n * EE + k] = (f16)Wv[k * EE + n];
        } else {
            woh[n * EE + k] = (f16)Wo[k * EE + n];
        }
    } else {
        const float* src = (y == 4) ? q : kv;
        f16* dh = (y == 4) ? qAhi : kvAhi;
        f16* dl = (y == 4) ? qAlo : kvAlo;
        int base = (blockIdx.x * 256 + t) * 8;
        float4 a = *(const float4*)&src[base];
        float4 c = *(const float4*)&src[base + 4];
        float xs[8] = {a.x, a.y, a.z, a.w, c.x, c.y, c.z, c.w};
        f16x8 hi, lo;
#pragma unroll
        for (int e = 0; e < 8; ++e) {
            f16 hh = (f16)xs[e];
            hi[e] = hh;
            lo[e] = (f16)(xs[e] - (float)hh);
        }
        *(f16x8*)&dh[base] = hi;
        *(f16x8*)&dl[base] = lo;
    }
}

// ---------------------------------------------------------------------------
// Fused projection with global_load_lds staging (m97 pattern).
// Grid (BT/128, EE/64, 2), block 256 (4 waves). Tile 128x64, BK=32.
// Linear LDS (no pad): A_s[buf][hi/lo][128][32], W_s[buf][h/l/v][64][32].
// DMA for k+1 issued before MFMA on k; 1 barrier per k-step.
// z=0: Q -> head planes. z=1: K' -> frag-packed kthi/ktlo, V -> packed vP.
// ---------------------------------------------------------------------------
__global__ __launch_bounds__(256) void proj_k(
    const f16* __restrict__ qAhi, const f16* __restrict__ qAlo,
    const f16* __restrict__ kvAhi, const f16* __restrict__ kvAlo,
    const f16* __restrict__ wqh, const f16* __restrict__ wql,
    const f16* __restrict__ wkh, const f16* __restrict__ wkl,
    const f16* __restrict__ wvh,
    f16* __restrict__ qhi, f16* __restrict__ qlo,
    f16* __restrict__ kthi, f16* __restrict__ ktlo, f16* __restrict__ vP) {
    __shared__ __align__(16) f16 A_s[2][2][128][32];   // 32 KB
    __shared__ __align__(16) f16 W_s[2][3][64][32];    // 24 KB
    f16 (*Ep)[136] = reinterpret_cast<f16(*)[136]>(&A_s[0][0][0][0]);

    const int t = threadIdx.x;
    const int w = t >> 6, l = t & 63;
    const int wm = w >> 1, wn = w & 1;
    const int fr = l & 15, fc = l >> 4;
    const int m0b = blockIdx.x * 128;
    const int n0b = blockIdx.y * 64;
    const int z   = blockIdx.z;

    const f16* AH = z ? kvAhi : qAhi;
    const f16* AL = z ? kvAlo : qAlo;
    const f16* WH = z ? wkh : wqh;
    const f16* WL = z ? wkl : wql;

    f32x4 accK[4][2], accV[4][2];
#pragma unroll
    for (int i = 0; i < 4; ++i)
#pragma unroll
        for (int j = 0; j < 2; ++j) {
            accK[i][j] = f32x4{0.f, 0.f, 0.f, 0.f};
            accV[i][j] = f32x4{0.f, 0.f, 0.f, 0.f};
        }

    auto stageDMA = [&](int bf, int k0) {
        // A hi/lo: 8 KB each = 2 calls x 4 waves x 1KB
#pragma unroll
        for (int i = 0; i < 2; ++i) {
            int slot = (i * 4 + w) * 64 + l;        // 16B slot 0..511
            int r = slot >> 2, qv = slot & 3;       // row, 16B quarter
            const f16* gh = AH + (size_t)(m0b + r) * EE + k0 + qv * 8;
            const f16* gl = AL + (size_t)(m0b + r) * EE + k0 + qv * 8;
            dma16(gh, (char*)&A_s[bf][0][0][0] + (i * 4 + w) * 1024);
            dma16(gl, (char*)&A_s[bf][1][0][0] + (i * 4 + w) * 1024);
        }
        // W planes: 4 KB each = 1 call x 4 waves x 1KB
        {
            int slot = w * 64 + l;                  // 0..255
            int r = slot >> 2, qv = slot & 3;
            const f16* g0 = WH + (size_t)(n0b + r) * EE + k0 + qv * 8;
            const f16* g1 = WL + (size_t)(n0b + r) * EE + k0 + qv * 8;
            dma16(g0, (char*)&W_s[bf][0][0][0] + w * 1024);
            dma16(g1, (char*)&W_s[bf][1][0][0] + w * 1024);
            if (z) {
                const f16* g2 = wvh + (size_t)(n0b + r) * EE + k0 + qv * 8;
                dma16(g2, (char*)&W_s[bf][2][0][0] + w * 1024);
            }
        }
    };

    auto comp = [&](int bf) {
        f16x8 Ahf[4], Alf[4], Bh[2], Bl[2], Bv[2];
#pragma unroll
        for (int mi = 0; mi < 4; ++mi) {
            Ahf[mi] = *(const f16x8*)&A_s[bf][0][wm * 64 + mi * 16 + fr][fc * 8];
            Alf[mi] = *(const f16x8*)&A_s[bf][1][wm * 64 + mi * 16 + fr][fc * 8];
        }
#pragma unroll
        for (int nj = 0; nj < 2; ++nj) {
            Bh[nj] = *(const f16x8*)&W_s[bf][0][wn * 32 + nj * 16 + fr][fc * 8];
            Bl[nj] = *(const f16x8*)&W_s[bf][1][wn * 32 + nj * 16 + fr][fc * 8];
            if (z) Bv[nj] = *(const f16x8*)&W_s[bf][2][wn * 32 + nj * 16 + fr][fc * 8];
        }
        __builtin_amdgcn_s_setprio(1);
#pragma unroll
        for (int mi = 0; mi < 4; ++mi)
#pragma unroll
            for (int nj = 0; nj < 2; ++nj) {
                accK[mi][nj] = __builtin_amdgcn_mfma_f32_16x16x32_f16(
                    Ahf[mi], Bh[nj], accK[mi][nj], 0, 0, 0);
                accK[mi][nj] = __builtin_amdgcn_mfma_f32_16x16x32_f16(
                    Ahf[mi], Bl[nj], accK[mi][nj], 0, 0, 0);
                accK[mi][nj] = __builtin_amdgcn_mfma_f32_16x16x32_f16(
                    Alf[mi], Bh[nj], accK[mi][nj], 0, 0, 0);
                if (z)
                    accV[mi][nj] = __builtin_amdgcn_mfma_f32_16x16x32_f16(
                        Ahf[mi], Bv[nj], accV[mi][nj], 0, 0, 0);
            }
        __builtin_amdgcn_s_setprio(0);
    };

    stageDMA(0, 0);
    __syncthreads();
    int cur = 0;
    for (int ks = 0; ks < 16; ++ks) {
        if (ks < 15) stageDMA(cur ^ 1, (ks + 1) * 32);
        comp(cur);
        __syncthreads();
        cur ^= 1;
    }

    // ---- epilogue (Ep aliases dead A_s) ----
    const int d0  = n0b >> 3;            // first head-dim of this n-slice
    const int kfc = d0 >> 5;             // K-frag kf
    const int lg2 = (d0 >> 3) & 3;       // K-frag lane group
#pragma unroll
    for (int mi = 0; mi < 4; ++mi)
#pragma unroll
        for (int nj = 0; nj < 2; ++nj)
#pragma unroll
            for (int r = 0; r < 4; ++r)
                Ep[wn * 32 + nj * 16 + fr][wm * 64 + mi * 16 + fc * 4 + r] =
                    (f16)accK[mi][nj][r];
    __syncthreads();
#pragma unroll
    for (int i = 0; i < 4; ++i) {
        int task = t * 4 + i;            // (mr 0..127, h 0..7)
        int mr = task >> 3, h = task & 7;
        f16x8 v;
#pragma unroll
        for (int d = 0; d < 8; ++d) v[d] = Ep[8 * d + h][mr];
        if (z == 0) {
            *(f16x8*)&qhi[((size_t)h * BT + m0b + mr) * DD + d0] = v;
        } else {
            int mg = m0b + mr;
            int bb = mg >> 10, key = mg & 1023;
            size_t off = ((((((size_t)h * BB + bb) * 16 + (key >> 6)) * 4 +
                            ((key >> 4) & 3)) * 2 + kfc) * 64 +
                          lg2 * 16 + (key & 15)) * 8;
            *(f16x8*)&kthi[off] = v;
        }
    }
    __syncthreads();
#pragma unroll
    for (int mi = 0; mi < 4; ++mi)
#pragma unroll
        for (int nj = 0; nj < 2; ++nj)
#pragma unroll
            for (int r = 0; r < 4; ++r) {
                float x = accK[mi][nj][r];
                f16 hh = (f16)x;
                Ep[wn * 32 + nj * 16 + fr][wm * 64 + mi * 16 + fc * 4 + r] =
                    (f16)(x - (float)hh);
            }
    __syncthreads();
#pragma unroll
    for (int i = 0; i < 4; ++i) {
        int task = t * 4 + i;
        int mr = task >> 3, h = task & 7;
        f16x8 v;
#pragma unroll
        for (int d = 0; d < 8; ++d) v[d] = Ep[8 * d + h][mr];
        if (z == 0) {
            *(f16x8*)&qlo[((size_t)h * BT + m0b + mr) * DD + d0] = v;
        } else {
            int mg = m0b + mr;
            int bb = mg >> 10, key = mg & 1023;
            size_t off = ((((((size_t)h * BB + bb) * 16 + (key >> 6)) * 4 +
                            ((key >> 4) & 3)) * 2 + kfc) * 64 +
                          lg2 * 16 + (key & 15)) * 8;
            *(f16x8*)&ktlo[off] = v;
        }
    }
    if (z) {
        __syncthreads();
#pragma unroll
        for (int mi = 0; mi < 4; ++mi)
#pragma unroll
            for (int nj = 0; nj < 2; ++nj)
#pragma unroll
                for (int r = 0; r < 4; ++r)
                    Ep[wn * 32 + nj * 16 + fr][wm * 64 + mi * 16 + fc * 4 + r] =
                        (f16)accV[mi][nj][r];
        __syncthreads();
        // V fragment-packed store: vP[h][tile][kf][dvt][lane][8]
#pragma unroll
        for (int i = 0; i < 4; ++i) {
            int task = t * 4 + i;           // (nn 0..63, mg 0..15)
            int mg = task & 15, nn = task >> 4;
            int h = nn & 7, dl = nn >> 3;
            int d = d0 + dl;
            int koff = m0b + mg * 8;
            int tile = koff >> 6;
            int kf   = (koff >> 5) & 1;
            int lgv  = (koff >> 3) & 3;
            int dvt  = d >> 4, lqd = d & 15;
            f16x8 v = *(const f16x8*)&Ep[nn][mg * 8];
            size_t off = (((((size_t)h * 64 + tile) * 2 + kf) * 4 + dvt) * 64 +
                          lgv * 16 + lqd) * 8;
            *(f16x8*)&vP[off] = v;
        }
    }
}

// ---------------------------------------------------------------------------
// Output GEMM: out = ctx(f16) @ Wo (f16) -> fp32. Tile 64x64, BK=64.
// ---------------------------------------------------------------------------
__global__ __launch_bounds__(256) void outmm_k(const f16* __restrict__ Af,
                                               const f16* __restrict__ WThi,
                                               float* __restrict__ out) {
    __shared__ __align__(16) f16 Ah_s[2][64][72];
    __shared__ __align__(16) f16 Wh_s[2][64][72];

    const int t = threadIdx.x;
    const int w = t >> 6, l = t & 63;
    const int wm = w >> 1, wn = w & 1;
    const int fr = l & 15, fc = l >> 4;
    const int m0b = blockIdx.x * 64;
    const int n0b = blockIdx.y * 64;
    const int sr = t >> 2, sch = t & 3;

    f32x4 acc[2][2];
#pragma unroll
    for (int i = 0; i < 2; ++i)
#pragma unroll
        for (int j = 0; j < 2; ++j) acc[i][j] = f32x4{0.f, 0.f, 0.f, 0.f};

    f16x8 af[2], wf[2];
    auto loadAB = [&](int k0) {
#pragma unroll
        for (int i = 0; i < 2; ++i) {
            af[i] = *(const f16x8*)&Af[(size_t)(m0b + sr) * EE + k0 + sch * 16 + i * 8];
            wf[i] = *(const f16x8*)&WThi[(size_t)(n0b + sr) * EE + k0 + sch * 16 + i * 8];
        }
    };
    auto stage = [&](int bf) {
#pragma unroll
        for (int i = 0; i < 2; ++i) {
            *(f16x8*)&Ah_s[bf][sr][sch * 16 + i * 8] = af[i];
            *(f16x8*)&Wh_s[bf][sr][sch * 16 + i * 8] = wf[i];
        }
    };

    loadAB(0);
    stage(0);
    __syncthreads();
    int cur = 0;
    for (int ks = 0; ks < 8; ++ks) {
        if (ks < 7) loadAB((ks + 1) * 64);
        f16x8 Ahf[2][2], Bhf[2][2];
#pragma unroll
        for (int mi = 0; mi < 2; ++mi)
#pragma unroll
            for (int kb = 0; kb < 2; ++kb)
                Ahf[mi][kb] =
                    *(const f16x8*)&Ah_s[cur][wm * 32 + mi * 16 + fr][kb * 32 + fc * 8];
#pragma unroll
        for (int nj = 0; nj < 2; ++nj)
#pragma unroll
            for (int kb = 0; kb < 2; ++kb)
                Bhf[nj][kb] =
                    *(const f16x8*)&Wh_s[cur][wn * 32 + nj * 16 + fr][kb * 32 + fc * 8];
        __builtin_amdgcn_s_setprio(1);
#pragma unroll
        for (int mi = 0; mi < 2; ++mi)
#pragma unroll
            for (int nj = 0; nj < 2; ++nj)
#pragma unroll
                for (int kb = 0; kb < 2; ++kb)
                    acc[mi][nj] = __builtin_amdgcn_mfma_f32_16x16x32_f16(
                        Ahf[mi][kb], Bhf[nj][kb], acc[mi][nj], 0, 0, 0);
        __builtin_amdgcn_s_setprio(0);
        if (ks < 7) stage(cur ^ 1);
        __syncthreads();
        cur ^= 1;
    }

#pragma unroll
    for (int mi = 0; mi < 2; ++mi)
#pragma unroll
        for (int nj = 0; nj < 2; ++nj)
#pragma unroll
            for (int r = 0; r < 4; ++r)
                out[(size_t)(m0b + wm * 32 + mi * 16 + fc * 4 + r) * EE +
                    n0b + wn * 32 + nj * 16 + fr] = acc[mi][nj][r];
}

// ---------------------------------------------------------------------------
// Barrier-free MFMA flash attention (unchanged from R11). K/V fragments via
// coalesced packed global loads into registers; zero __syncthreads.
// ---------------------------------------------------------------------------
__global__ __launch_bounds__(256) void attn_mfma_k(const f16* __restrict__ qhiP,
    const f16* __restrict__ qloP, const f16* __restrict__ kthiP,
    const f16* __restrict__ ktloP, const f16* __restrict__ vP,
    f16* __restrict__ ctx) {
    __shared__ __align__(16) f16 Pl[4][16][88];    // per-wave P[q][key]

    const int bid = blockIdx.x;                 // 0..511
    const int swz = (bid & 7) * 64 + (bid >> 3);
    const int bx = swz & 15;
    const int h  = (swz >> 4) & 7;
    const int b  = swz >> 7;

    const int t  = threadIdx.x;
    const int w  = t >> 6;
    const int l  = t & 63;
    const int lg = l >> 4;
    const int lq = l & 15;
    const int q0 = bx * 64 + w * 16;
    const size_t plane = ((size_t)h * BT + (size_t)b * TT) * DD;

    f16x8 Qhi[2], Qlo[2];
#pragma unroll
    for (int kf = 0; kf < 2; ++kf) {
        size_t qo = plane + (size_t)(q0 + lq) * DD + kf * 32 + lg * 8;
        Qhi[kf] = *(const f16x8*)&qhiP[qo];
        Qlo[kf] = *(const f16x8*)&qloP[qo];
    }

    f32x4 Oacc[4];
#pragma unroll
    for (int i = 0; i < 4; ++i) Oacc[i] = f32x4{0.f, 0.f, 0.f, 0.f};
    float m = -1e30f, lsum = 0.f;

    const f16* khb = kthiP + (((size_t)h * BB + b) << 16);
    const f16* klb = ktloP + (((size_t)h * BB + b) << 16);

    f16x8 kA[4], kB[4];
    auto LK = [&](int kt64, int kt, f16x8 (&s)[4]) {
        size_t o = ((size_t)kt64 * 4 + kt) * 1024 + l * 8;
        s[0] = *(const f16x8*)&khb[o];
        s[1] = *(const f16x8*)&khb[o + 512];
        s[2] = *(const f16x8*)&klb[o];
        s[3] = *(const f16x8*)&klb[o + 512];
    };
    auto QK1 = [&](const f16x8 (&s)[4]) -> f32x4 {
        f32x4 c = f32x4{0.f, 0.f, 0.f, 0.f};
        __builtin_amdgcn_s_setprio(1);
        c = __builtin_amdgcn_mfma_f32_16x16x32_f16(s[0], Qhi[0], c, 0, 0, 0);
        c = __builtin_amdgcn_mfma_f32_16x16x32_f16(s[0], Qlo[0], c, 0, 0, 0);
        c = __builtin_amdgcn_mfma_f32_16x16x32_f16(s[2], Qhi[0], c, 0, 0, 0);
        c = __builtin_amdgcn_mfma_f32_16x16x32_f16(s[1], Qhi[1], c, 0, 0, 0);
        c = __builtin_amdgcn_mfma_f32_16x16x32_f16(s[1], Qlo[1], c, 0, 0, 0);
        c = __builtin_amdgcn_mfma_f32_16x16x32_f16(s[3], Qhi[1], c, 0, 0, 0);
        __builtin_amdgcn_s_setprio(0);
        return c;
    };

    f16x8 bvA[2][4], bvB[2][4];
    auto loadBV = [&](int tile, f16x8 (&bv)[2][4]) {
        const f16* tb = vP + ((size_t)h * 64 + b * 16 + tile) * 4096;
#pragma unroll
        for (int kf = 0; kf < 2; ++kf)
#pragma unroll
            for (int dvt = 0; dvt < 4; ++dvt)
                bv[kf][dvt] = *(const f16x8*)&tb[((kf * 4 + dvt) * 64 + l) * 8];
    };

    auto SMPV = [&](const f32x4 (&Sc)[4], const f16x8 (&bv)[2][4]) {
        float sv[16];
#pragma unroll
        for (int kt = 0; kt < 4; ++kt)
#pragma unroll
            for (int r = 0; r < 4; ++r) sv[kt * 4 + r] = Sc[kt][r];
        float tm = sv[0];
#pragma unroll
        for (int i = 1; i < 16; ++i) tm = fmaxf(tm, sv[i]);
        tm = fmaxf(tm, __shfl_xor(tm, 16));
        tm = fmaxf(tm, __shfl_xor(tm, 32));

        bool skip = __all(tm <= m + 8.0f);
        float Mn = m, corr = 1.0f;
        if (!skip) {
            Mn = fmaxf(m, tm);
            corr = __expf(m - Mn);
        }
        float ps = 0.f;
        f16 ph[16];
#pragma unroll
        for (int i = 0; i < 16; ++i) {
            float p = __expf(sv[i] - Mn);
            ps += p;
            ph[i] = (f16)p;
        }
        ps += __shfl_xor(ps, 16);
        ps += __shfl_xor(ps, 32);
        if (skip) {
            lsum += ps;
        } else {
            lsum = lsum * corr + ps;
            m = Mn;
        }

#pragma unroll
        for (int kt = 0; kt < 4; ++kt)
#pragma unroll
            for (int rp = 0; rp < 4; rp += 2) {
                union { f16 h; unsigned short u; } u0, u1;
                u0.h = ph[kt * 4 + rp]; u1.h = ph[kt * 4 + rp + 1];
                unsigned int pk = ((unsigned int)u1.u << 16) | u0.u;
                *(unsigned int*)&Pl[w][lq][kt * 16 + lg * 4 + rp] = pk;
            }

        if (!skip) {
            float cq[4];
#pragma unroll
            for (int r = 0; r < 4; ++r) cq[r] = __shfl(corr, lg * 4 + r);
#pragma unroll
            for (int dvt = 0; dvt < 4; ++dvt)
#pragma unroll
                for (int r = 0; r < 4; ++r) Oacc[dvt][r] *= cq[r];
        }

        __builtin_amdgcn_s_setprio(1);
#pragma unroll
        for (int kf = 0; kf < 2; ++kf) {
            f16x8 pa = *(const f16x8*)&Pl[w][lq][kf * 32 + lg * 8];
#pragma unroll
            for (int dvt = 0; dvt < 4; ++dvt)
                Oacc[dvt] = __builtin_amdgcn_mfma_f32_16x16x32_f16(
                    pa, bv[kf][dvt], Oacc[dvt], 0, 0, 0);
        }
        __builtin_amdgcn_s_setprio(0);
    };

    LK(0, 0, kA);
    loadBV(0, bvA);
    f32x4 Sc[4];

    for (int tile = 0; tile < 16; tile += 2) {
        LK(tile, 1, kB);      Sc[0] = QK1(kA);
        LK(tile, 2, kA);      Sc[1] = QK1(kB);
        LK(tile, 3, kB);      Sc[2] = QK1(kA);
        LK(tile + 1, 0, kA);  Sc[3] = QK1(kB);
        loadBV(tile + 1, bvB);
        SMPV(Sc, bvA);
        LK(tile + 1, 1, kB);  Sc[0] = QK1(kA);
        LK(tile + 1, 2, kA);  Sc[1] = QK1(kB);
        LK(tile + 1, 3, kB);  Sc[2] = QK1(kA);
        if (tile + 2 < 16) LK(tile + 2, 0, kA);
        Sc[3] = QK1(kB);
        if (tile + 2 < 16) loadBV(tile + 2, bvA);
        SMPV(Sc, bvB);
    }

    float linv = 1.0f / lsum;
    float lq4[4];
#pragma unroll
    for (int r = 0; r < 4; ++r) lq4[r] = __shfl(linv, lg * 4 + r);
#pragma unroll
    for (int r = 0; r < 4; ++r) {
        f16* crow = ctx + (size_t)(b * TT + q0 + lg * 4 + r) * EE + h * DD;
#pragma unroll
        for (int dvt = 0; dvt < 4; ++dvt)
            crow[dvt * 16 + lq] = (f16)(Oacc[dvt][r] * lq4[r]);
    }
}

// ---------------------------------------------------------------------------
extern "C" void kernel_launch(void* const* d_in, const int* in_sizes, int n_in,
                              void* d_out, int out_size, void* d_ws, size_t ws_size,
                              hipStream_t stream) {
    const float* q  = (const float*)d_in[0];
    const float* kv = (const float*)d_in[1];
    const float* Wq = (const float*)d_in[2];
    const float* Wk = (const float*)d_in[3];
    const float* Wv = (const float*)d_in[4];
    const float* Wo = (const float*)d_in[5];
    float* out = (float*)d_out;

    f16* ws = (f16*)d_ws;
    const size_t PL  = (size_t)HH * BT * DD;   // 2,097,152 f16 per plane
    const size_t WPL = (size_t)EE * EE;
    f16* qhi   = ws + 0 * PL;
    f16* qlo   = ws + 1 * PL;
    f16* kthi  = ws + 2 * PL;      // packed K frags [H][B][16][4][2][64][8]
    f16* ktlo  = ws + 3 * PL;
    f16* vPck  = ws + 4 * PL;      // packed V frags [H][64][2][4][64][8]
    f16* ctx   = ws + 5 * PL;      // [BT][512]
    f16* qAhi  = ws + 6 * PL;
    f16* qAlo  = ws + 7 * PL;
    f16* kvAhi = ws + 8 * PL;
    f16* kvAlo = ws + 9 * PL;
    f16* wqh = ws + 10 * PL;
    f16* wql = wqh + 1 * WPL;
    f16* wkh = wqh + 2 * WPL;
    f16* wkl = wqh + 3 * WPL;
    f16* wvh = wqh + 4 * WPL;
    f16* woh = wqh + 5 * WPL;

    prep_k<<<dim3(1024, 6), dim3(256), 0, stream>>>(
        q, kv, Wq, Wk, Wv, Wo, wqh, wql, wkh, wkl, wvh, woh,
        qAhi, qAlo, kvAhi, kvAlo);

    proj_k<<<dim3(BT / 128, EE / 64, 2), dim3(256), 0, stream>>>(
        qAhi, qAlo, kvAhi, kvAlo, wqh, wql, wkh, wkl, wvh,
        qhi, qlo, kthi, ktlo, vPck);

    attn_mfma_k<<<dim3(512), dim3(256), 0, stream>>>(
        qhi, qlo, kthi, ktlo, vPck, ctx);

    outmm_k<<<dim3(BT / 64, EE / 64), dim3(256), 0, stream>>>(ctx, woh, out);
}

// Round 13
// 75.549 us; speedup vs baseline: 1.0347x; 1.0233x over previous
//
#include <hip/hip_runtime.h>
#include <math.h>

#define BB 4
#define TT 1024
#define EE 512
#define HH 8
#define DD 64
#define BT (BB * TT)   // 4096

typedef _Float16 f16;
typedef __attribute__((ext_vector_type(8))) _Float16 f16x8;
typedef __attribute__((ext_vector_type(4))) float f32x4;

// direct global->LDS DMA, 16B per lane. LDS dest = wave-uniform base + lane*16.
__device__ __forceinline__ void dma16(const f16* g, char* l) {
    __builtin_amdgcn_global_load_lds(
        (const __attribute__((address_space(1))) void*)g,
        (__attribute__((address_space(3))) void*)l, 16, 0, 0);
}

// ---------------------------------------------------------------------------
// Prep: y=0..3 weight planes (transposed f16), y=4/5 split q/kv into hi+lo
// f16 planes [BT][512]. Grid (1024, 6).
// ---------------------------------------------------------------------------
__global__ __launch_bounds__(256) void prep_k(
    const float* __restrict__ q, const float* __restrict__ kv,
    const float* __restrict__ Wq, const float* __restrict__ Wk,
    const float* __restrict__ Wv, const float* __restrict__ Wo,
    f16* __restrict__ wqh, f16* __restrict__ wql,
    f16* __restrict__ wkh, f16* __restrict__ wkl,
    f16* __restrict__ wvh, f16* __restrict__ woh,
    f16* __restrict__ qAhi, f16* __restrict__ qAlo,
    f16* __restrict__ kvAhi, f16* __restrict__ kvAlo) {
    const int t = threadIdx.x;
    const int y = blockIdx.y;
    if (y < 4) {
        int idx = blockIdx.x * 256 + t;        // 512*512 elems
        int k = idx & (EE - 1);
        int n = idx >> 9;
        if (y == 0) {
            float v = Wq[k * EE + n] * 512.0f; // fold dk*D scale (exact pow2)
            f16 hi = (f16)v;
            wqh[n * EE + k] = hi;
            wql[n * EE + k] = (f16)(v - (float)hi);
        } else if (y == 1) {
            int d = n >> 3, h = n & 7;
            int sn = (((DD - d) & (DD - 1)) << 3) | h;  // K'[.,d]=K[.,(D-d)%D]
            float v = Wk[k * EE + sn];
            f16 hi = (f16)v;
            wkh[n * EE + k] = hi;
            wkl[n * EE + k] = (f16)(v - (float)hi);
        } else if (y == 2) {
            wvh[n * EE + k] = (f16)Wv[k * EE + n];
        } else {
            woh[n * EE + k] = (f16)Wo[k * EE + n];
        }
    } else {
        const float* src = (y == 4) ? q : kv;
        f16* dh = (y == 4) ? qAhi : kvAhi;
        f16* dl = (y == 4) ? qAlo : kvAlo;
        int base = (blockIdx.x * 256 + t) * 8;
        float4 a = *(const float4*)&src[base];
        float4 c = *(const float4*)&src[base + 4];
        float xs[8] = {a.x, a.y, a.z, a.w, c.x, c.y, c.z, c.w};
        f16x8 hi, lo;
#pragma unroll
        for (int e = 0; e < 8; ++e) {
            f16 hh = (f16)xs[e];
            hi[e] = hh;
            lo[e] = (f16)(xs[e] - (float)hh);
        }
        *(f16x8*)&dh[base] = hi;
        *(f16x8*)&dl[base] = lo;
    }
}

// ---------------------------------------------------------------------------
// Fused projection with global_load_lds staging (unchanged from R12).
// Grid (BT/128, EE/64, 2), block 256 (4 waves). Tile 128x64, BK=32.
// z=0: Q -> head planes. z=1: K' -> frag-packed kthi/ktlo, V -> packed vP.
// ---------------------------------------------------------------------------
__global__ __launch_bounds__(256) void proj_k(
    const f16* __restrict__ qAhi, const f16* __restrict__ qAlo,
    const f16* __restrict__ kvAhi, const f16* __restrict__ kvAlo,
    const f16* __restrict__ wqh, const f16* __restrict__ wql,
    const f16* __restrict__ wkh, const f16* __restrict__ wkl,
    const f16* __restrict__ wvh,
    f16* __restrict__ qhi, f16* __restrict__ qlo,
    f16* __restrict__ kthi, f16* __restrict__ ktlo, f16* __restrict__ vP) {
    __shared__ __align__(16) f16 A_s[2][2][128][32];   // 32 KB
    __shared__ __align__(16) f16 W_s[2][3][64][32];    // 24 KB
    f16 (*Ep)[136] = reinterpret_cast<f16(*)[136]>(&A_s[0][0][0][0]);

    const int t = threadIdx.x;
    const int w = t >> 6, l = t & 63;
    const int wm = w >> 1, wn = w & 1;
    const int fr = l & 15, fc = l >> 4;
    const int m0b = blockIdx.x * 128;
    const int n0b = blockIdx.y * 64;
    const int z   = blockIdx.z;

    const f16* AH = z ? kvAhi : qAhi;
    const f16* AL = z ? kvAlo : qAlo;
    const f16* WH = z ? wkh : wqh;
    const f16* WL = z ? wkl : wql;

    f32x4 accK[4][2], accV[4][2];
#pragma unroll
    for (int i = 0; i < 4; ++i)
#pragma unroll
        for (int j = 0; j < 2; ++j) {
            accK[i][j] = f32x4{0.f, 0.f, 0.f, 0.f};
            accV[i][j] = f32x4{0.f, 0.f, 0.f, 0.f};
        }

    auto stageDMA = [&](int bf, int k0) {
#pragma unroll
        for (int i = 0; i < 2; ++i) {
            int slot = (i * 4 + w) * 64 + l;
            int r = slot >> 2, qv = slot & 3;
            const f16* gh = AH + (size_t)(m0b + r) * EE + k0 + qv * 8;
            const f16* gl = AL + (size_t)(m0b + r) * EE + k0 + qv * 8;
            dma16(gh, (char*)&A_s[bf][0][0][0] + (i * 4 + w) * 1024);
            dma16(gl, (char*)&A_s[bf][1][0][0] + (i * 4 + w) * 1024);
        }
        {
            int slot = w * 64 + l;
            int r = slot >> 2, qv = slot & 3;
            const f16* g0 = WH + (size_t)(n0b + r) * EE + k0 + qv * 8;
            const f16* g1 = WL + (size_t)(n0b + r) * EE + k0 + qv * 8;
            dma16(g0, (char*)&W_s[bf][0][0][0] + w * 1024);
            dma16(g1, (char*)&W_s[bf][1][0][0] + w * 1024);
            if (z) {
                const f16* g2 = wvh + (size_t)(n0b + r) * EE + k0 + qv * 8;
                dma16(g2, (char*)&W_s[bf][2][0][0] + w * 1024);
            }
        }
    };

    auto comp = [&](int bf) {
        f16x8 Ahf[4], Alf[4], Bh[2], Bl[2], Bv[2];
#pragma unroll
        for (int mi = 0; mi < 4; ++mi) {
            Ahf[mi] = *(const f16x8*)&A_s[bf][0][wm * 64 + mi * 16 + fr][fc * 8];
            Alf[mi] = *(const f16x8*)&A_s[bf][1][wm * 64 + mi * 16 + fr][fc * 8];
        }
#pragma unroll
        for (int nj = 0; nj < 2; ++nj) {
            Bh[nj] = *(const f16x8*)&W_s[bf][0][wn * 32 + nj * 16 + fr][fc * 8];
            Bl[nj] = *(const f16x8*)&W_s[bf][1][wn * 32 + nj * 16 + fr][fc * 8];
            if (z) Bv[nj] = *(const f16x8*)&W_s[bf][2][wn * 32 + nj * 16 + fr][fc * 8];
        }
        __builtin_amdgcn_s_setprio(1);
#pragma unroll
        for (int mi = 0; mi < 4; ++mi)
#pragma unroll
            for (int nj = 0; nj < 2; ++nj) {
                accK[mi][nj] = __builtin_amdgcn_mfma_f32_16x16x32_f16(
                    Ahf[mi], Bh[nj], accK[mi][nj], 0, 0, 0);
                accK[mi][nj] = __builtin_amdgcn_mfma_f32_16x16x32_f16(
                    Ahf[mi], Bl[nj], accK[mi][nj], 0, 0, 0);
                accK[mi][nj] = __builtin_amdgcn_mfma_f32_16x16x32_f16(
                    Alf[mi], Bh[nj], accK[mi][nj], 0, 0, 0);
                if (z)
                    accV[mi][nj] = __builtin_amdgcn_mfma_f32_16x16x32_f16(
                        Ahf[mi], Bv[nj], accV[mi][nj], 0, 0, 0);
            }
        __builtin_amdgcn_s_setprio(0);
    };

    stageDMA(0, 0);
    __syncthreads();
    int cur = 0;
    for (int ks = 0; ks < 16; ++ks) {
        if (ks < 15) stageDMA(cur ^ 1, (ks + 1) * 32);
        comp(cur);
        __syncthreads();
        cur ^= 1;
    }

    // ---- epilogue (Ep aliases dead A_s) ----
    const int d0  = n0b >> 3;
    const int kfc = d0 >> 5;
    const int lg2 = (d0 >> 3) & 3;
#pragma unroll
    for (int mi = 0; mi < 4; ++mi)
#pragma unroll
        for (int nj = 0; nj < 2; ++nj)
#pragma unroll
            for (int r = 0; r < 4; ++r)
                Ep[wn * 32 + nj * 16 + fr][wm * 64 + mi * 16 + fc * 4 + r] =
                    (f16)accK[mi][nj][r];
    __syncthreads();
#pragma unroll
    for (int i = 0; i < 4; ++i) {
        int task = t * 4 + i;
        int mr = task >> 3, h = task & 7;
        f16x8 v;
#pragma unroll
        for (int d = 0; d < 8; ++d) v[d] = Ep[8 * d + h][mr];
        if (z == 0) {
            *(f16x8*)&qhi[((size_t)h * BT + m0b + mr) * DD + d0] = v;
        } else {
            int mg = m0b + mr;
            int bb = mg >> 10, key = mg & 1023;
            size_t off = ((((((size_t)h * BB + bb) * 16 + (key >> 6)) * 4 +
                            ((key >> 4) & 3)) * 2 + kfc) * 64 +
                          lg2 * 16 + (key & 15)) * 8;
            *(f16x8*)&kthi[off] = v;
        }
    }
    __syncthreads();
#pragma unroll
    for (int mi = 0; mi < 4; ++mi)
#pragma unroll
        for (int nj = 0; nj < 2; ++nj)
#pragma unroll
            for (int r = 0; r < 4; ++r) {
                float x = accK[mi][nj][r];
                f16 hh = (f16)x;
                Ep[wn * 32 + nj * 16 + fr][wm * 64 + mi * 16 + fc * 4 + r] =
                    (f16)(x - (float)hh);
            }
    __syncthreads();
#pragma unroll
    for (int i = 0; i < 4; ++i) {
        int task = t * 4 + i;
        int mr = task >> 3, h = task & 7;
        f16x8 v;
#pragma unroll
        for (int d = 0; d < 8; ++d) v[d] = Ep[8 * d + h][mr];
        if (z == 0) {
            *(f16x8*)&qlo[((size_t)h * BT + m0b + mr) * DD + d0] = v;
        } else {
            int mg = m0b + mr;
            int bb = mg >> 10, key = mg & 1023;
            size_t off = ((((((size_t)h * BB + bb) * 16 + (key >> 6)) * 4 +
                            ((key >> 4) & 3)) * 2 + kfc) * 64 +
                          lg2 * 16 + (key & 15)) * 8;
            *(f16x8*)&ktlo[off] = v;
        }
    }
    if (z) {
        __syncthreads();
#pragma unroll
        for (int mi = 0; mi < 4; ++mi)
#pragma unroll
            for (int nj = 0; nj < 2; ++nj)
#pragma unroll
                for (int r = 0; r < 4; ++r)
                    Ep[wn * 32 + nj * 16 + fr][wm * 64 + mi * 16 + fc * 4 + r] =
                        (f16)accV[mi][nj][r];
        __syncthreads();
        // V fragment-packed store: vP[h][tile][kf][dvt][lane][8]
#pragma unroll
        for (int i = 0; i < 4; ++i) {
            int task = t * 4 + i;
            int mg = task & 15, nn = task >> 4;
            int h = nn & 7, dl = nn >> 3;
            int d = d0 + dl;
            int koff = m0b + mg * 8;
            int tile = koff >> 6;
            int kf   = (koff >> 5) & 1;
            int lgv  = (koff >> 3) & 3;
            int dvt  = d >> 4, lqd = d & 15;
            f16x8 v = *(const f16x8*)&Ep[nn][mg * 8];
            size_t off = (((((size_t)h * 64 + tile) * 2 + kf) * 4 + dvt) * 64 +
                          lgv * 16 + lqd) * 8;
            *(f16x8*)&vP[off] = v;
        }
    }
}

// ---------------------------------------------------------------------------
// Output GEMM: out = ctx(f16) @ Wo (f16) -> fp32. Tile 64x64, BK=64.
// ---------------------------------------------------------------------------
__global__ __launch_bounds__(256) void outmm_k(const f16* __restrict__ Af,
                                               const f16* __restrict__ WThi,
                                               float* __restrict__ out) {
    __shared__ __align__(16) f16 Ah_s[2][64][72];
    __shared__ __align__(16) f16 Wh_s[2][64][72];

    const int t = threadIdx.x;
    const int w = t >> 6, l = t & 63;
    const int wm = w >> 1, wn = w & 1;
    const int fr = l & 15, fc = l >> 4;
    const int m0b = blockIdx.x * 64;
    const int n0b = blockIdx.y * 64;
    const int sr = t >> 2, sch = t & 3;

    f32x4 acc[2][2];
#pragma unroll
    for (int i = 0; i < 2; ++i)
#pragma unroll
        for (int j = 0; j < 2; ++j) acc[i][j] = f32x4{0.f, 0.f, 0.f, 0.f};

    f16x8 af[2], wf[2];
    auto loadAB = [&](int k0) {
#pragma unroll
        for (int i = 0; i < 2; ++i) {
            af[i] = *(const f16x8*)&Af[(size_t)(m0b + sr) * EE + k0 + sch * 16 + i * 8];
            wf[i] = *(const f16x8*)&WThi[(size_t)(n0b + sr) * EE + k0 + sch * 16 + i * 8];
        }
    };
    auto stage = [&](int bf) {
#pragma unroll
        for (int i = 0; i < 2; ++i) {
            *(f16x8*)&Ah_s[bf][sr][sch * 16 + i * 8] = af[i];
            *(f16x8*)&Wh_s[bf][sr][sch * 16 + i * 8] = wf[i];
        }
    };

    loadAB(0);
    stage(0);
    __syncthreads();
    int cur = 0;
    for (int ks = 0; ks < 8; ++ks) {
        if (ks < 7) loadAB((ks + 1) * 64);
        f16x8 Ahf[2][2], Bhf[2][2];
#pragma unroll
        for (int mi = 0; mi < 2; ++mi)
#pragma unroll
            for (int kb = 0; kb < 2; ++kb)
                Ahf[mi][kb] =
                    *(const f16x8*)&Ah_s[cur][wm * 32 + mi * 16 + fr][kb * 32 + fc * 8];
#pragma unroll
        for (int nj = 0; nj < 2; ++nj)
#pragma unroll
            for (int kb = 0; kb < 2; ++kb)
                Bhf[nj][kb] =
                    *(const f16x8*)&Wh_s[cur][wn * 32 + nj * 16 + fr][kb * 32 + fc * 8];
        __builtin_amdgcn_s_setprio(1);
#pragma unroll
        for (int mi = 0; mi < 2; ++mi)
#pragma unroll
            for (int nj = 0; nj < 2; ++nj)
#pragma unroll
                for (int kb = 0; kb < 2; ++kb)
                    acc[mi][nj] = __builtin_amdgcn_mfma_f32_16x16x32_f16(
                        Ahf[mi][kb], Bhf[nj][kb], acc[mi][nj], 0, 0, 0);
        __builtin_amdgcn_s_setprio(0);
        if (ks < 7) stage(cur ^ 1);
        __syncthreads();
        cur ^= 1;
    }

#pragma unroll
    for (int mi = 0; mi < 2; ++mi)
#pragma unroll
        for (int nj = 0; nj < 2; ++nj)
#pragma unroll
            for (int r = 0; r < 4; ++r)
                out[(size_t)(m0b + wm * 32 + mi * 16 + fc * 4 + r) * EE +
                    n0b + wn * 32 + nj * 16 + fr] = acc[mi][nj][r];
}

// ---------------------------------------------------------------------------
// Block-shared LDS flash attention. Grid 256 blocks (h on bid&7 -> XCD-local),
// block = 8 waves x 16 q-rows = 128 q-rows of one (h,b). K hi/lo + V tiles
// staged per-block in LDS via pure global_load_lds DMA from the packed
// planes (3 x 16B per thread per tile); fragment reads are lane-contiguous
// b128, conflict-free. 1 barrier per tile; DMA issued a full tile ahead.
// ---------------------------------------------------------------------------
__global__ __launch_bounds__(512) void attn_mfma_k(const f16* __restrict__ qhiP,
    const f16* __restrict__ qloP, const f16* __restrict__ kthiP,
    const f16* __restrict__ ktloP, const f16* __restrict__ vP,
    f16* __restrict__ ctx) {
    __shared__ __align__(16) f16 KhiL[2][4096];    // 8 KB per buffer
    __shared__ __align__(16) f16 KloL[2][4096];
    __shared__ __align__(16) f16 VL[2][4096];
    __shared__ __align__(16) f16 Pl[8][16][88];    // per-wave P[q][key]

    const int bid = blockIdx.x;          // 0..255
    const int bx = (bid >> 3) & 7;       // q-block 0..7
    const int h  = bid & 7;              // same h -> same XCD
    const int b  = bid >> 6;

    const int t  = threadIdx.x;          // 0..511
    const int w  = t >> 6;
    const int l  = t & 63;
    const int lg = l >> 4;
    const int lq = l & 15;
    const int q0 = bx * 128 + w * 16;
    const size_t plane = ((size_t)h * BT + (size_t)b * TT) * DD;

    f16x8 Qhi[2], Qlo[2];
#pragma unroll
    for (int kf = 0; kf < 2; ++kf) {
        size_t qo = plane + (size_t)(q0 + lq) * DD + kf * 32 + lg * 8;
        Qhi[kf] = *(const f16x8*)&qhiP[qo];
        Qlo[kf] = *(const f16x8*)&qloP[qo];
    }

    f32x4 Oacc[4];
#pragma unroll
    for (int i = 0; i < 4; ++i) Oacc[i] = f32x4{0.f, 0.f, 0.f, 0.f};
    float m = -1e30f, lsum = 0.f;

    // packed tile bases: 4096 f16 (8 KB) contiguous per tile
    const f16* khb = kthiP + (((size_t)h * BB + b) << 16);
    const f16* klb = ktloP + (((size_t)h * BB + b) << 16);
    const f16* vtb = vP + ((size_t)h * 64 + b * 16) * 4096;

    auto stageDMA = [&](int bf, int tile) {
        const f16* ks = khb + (size_t)tile * 4096 + t * 8;
        const f16* ls = klb + (size_t)tile * 4096 + t * 8;
        const f16* vs = vtb + (size_t)tile * 4096 + t * 8;
        dma16(ks, (char*)&KhiL[bf][0] + w * 1024);
        dma16(ls, (char*)&KloL[bf][0] + w * 1024);
        dma16(vs, (char*)&VL[bf][0] + w * 1024);
    };

    auto QK1 = [&](int bf, int kt) -> f32x4 {
        const f16* bh = &KhiL[bf][kt * 1024];
        const f16* bl = &KloL[bf][kt * 1024];
        f16x8 s0 = *(const f16x8*)&bh[l * 8];
        f16x8 s1 = *(const f16x8*)&bh[512 + l * 8];
        f16x8 s2 = *(const f16x8*)&bl[l * 8];
        f16x8 s3 = *(const f16x8*)&bl[512 + l * 8];
        f32x4 c = f32x4{0.f, 0.f, 0.f, 0.f};
        __builtin_amdgcn_s_setprio(1);
        c = __builtin_amdgcn_mfma_f32_16x16x32_f16(s0, Qhi[0], c, 0, 0, 0);
        c = __builtin_amdgcn_mfma_f32_16x16x32_f16(s0, Qlo[0], c, 0, 0, 0);
        c = __builtin_amdgcn_mfma_f32_16x16x32_f16(s2, Qhi[0], c, 0, 0, 0);
        c = __builtin_amdgcn_mfma_f32_16x16x32_f16(s1, Qhi[1], c, 0, 0, 0);
        c = __builtin_amdgcn_mfma_f32_16x16x32_f16(s1, Qlo[1], c, 0, 0, 0);
        c = __builtin_amdgcn_mfma_f32_16x16x32_f16(s3, Qhi[1], c, 0, 0, 0);
        __builtin_amdgcn_s_setprio(0);
        return c;
    };

    auto SMPV = [&](int bf, const f32x4 (&Sc)[4]) {
        float sv[16];
#pragma unroll
        for (int kt = 0; kt < 4; ++kt)
#pragma unroll
            for (int r = 0; r < 4; ++r) sv[kt * 4 + r] = Sc[kt][r];
        float tm = sv[0];
#pragma unroll
        for (int i = 1; i < 16; ++i) tm = fmaxf(tm, sv[i]);
        tm = fmaxf(tm, __shfl_xor(tm, 16));
        tm = fmaxf(tm, __shfl_xor(tm, 32));

        bool skip = __all(tm <= m + 8.0f);
        float Mn = m, corr = 1.0f;
        if (!skip) {
            Mn = fmaxf(m, tm);
            corr = __expf(m - Mn);
        }
        float ps = 0.f;
        f16 ph[16];
#pragma unroll
        for (int i = 0; i < 16; ++i) {
            float p = __expf(sv[i] - Mn);
            ps += p;
            ph[i] = (f16)p;
        }
        ps += __shfl_xor(ps, 16);
        ps += __shfl_xor(ps, 32);
        if (skip) {
            lsum += ps;
        } else {
            lsum = lsum * corr + ps;
            m = Mn;
        }

#pragma unroll
        for (int kt = 0; kt < 4; ++kt)
#pragma unroll
            for (int rp = 0; rp < 4; rp += 2) {
                union { f16 h; unsigned short u; } u0, u1;
                u0.h = ph[kt * 4 + rp]; u1.h = ph[kt * 4 + rp + 1];
                unsigned int pk = ((unsigned int)u1.u << 16) | u0.u;
                *(unsigned int*)&Pl[w][lq][kt * 16 + lg * 4 + rp] = pk;
            }

        if (!skip) {
            float cq[4];
#pragma unroll
            for (int r = 0; r < 4; ++r) cq[r] = __shfl(corr, lg * 4 + r);
#pragma unroll
            for (int dvt = 0; dvt < 4; ++dvt)
#pragma unroll
                for (int r = 0; r < 4; ++r) Oacc[dvt][r] *= cq[r];
        }

        __builtin_amdgcn_s_setprio(1);
#pragma unroll
        for (int kf = 0; kf < 2; ++kf) {
            f16x8 pa = *(const f16x8*)&Pl[w][lq][kf * 32 + lg * 8];
#pragma unroll
            for (int dvt = 0; dvt < 4; ++dvt) {
                f16x8 bv = *(const f16x8*)&VL[bf][((kf * 4 + dvt) * 64 + l) * 8];
                Oacc[dvt] = __builtin_amdgcn_mfma_f32_16x16x32_f16(
                    pa, bv, Oacc[dvt], 0, 0, 0);
            }
        }
        __builtin_amdgcn_s_setprio(0);
    };

    stageDMA(0, 0);
    __syncthreads();
    int cur = 0;
    for (int tile = 0; tile < 16; ++tile) {
        if (tile + 1 < 16) stageDMA(cur ^ 1, tile + 1);   // DMA a tile ahead
        f32x4 Sc[4];
#pragma unroll
        for (int kt = 0; kt < 4; ++kt) Sc[kt] = QK1(cur, kt);
        SMPV(cur, Sc);
        __syncthreads();
        cur ^= 1;
    }

    float linv = 1.0f / lsum;
    float lq4[4];
#pragma unroll
    for (int r = 0; r < 4; ++r) lq4[r] = __shfl(linv, lg * 4 + r);
#pragma unroll
    for (int r = 0; r < 4; ++r) {
        f16* crow = ctx + (size_t)(b * TT + q0 + lg * 4 + r) * EE + h * DD;
#pragma unroll
        for (int dvt = 0; dvt < 4; ++dvt)
            crow[dvt * 16 + lq] = (f16)(Oacc[dvt][r] * lq4[r]);
    }
}

// ---------------------------------------------------------------------------
extern "C" void kernel_launch(void* const* d_in, const int* in_sizes, int n_in,
                              void* d_out, int out_size, void* d_ws, size_t ws_size,
                              hipStream_t stream) {
    const float* q  = (const float*)d_in[0];
    const float* kv = (const float*)d_in[1];
    const float* Wq = (const float*)d_in[2];
    const float* Wk = (const float*)d_in[3];
    const float* Wv = (const float*)d_in[4];
    const float* Wo = (const float*)d_in[5];
    float* out = (float*)d_out;

    f16* ws = (f16*)d_ws;
    const size_t PL  = (size_t)HH * BT * DD;   // 2,097,152 f16 per plane
    const size_t WPL = (size_t)EE * EE;
    f16* qhi   = ws + 0 * PL;
    f16* qlo   = ws + 1 * PL;
    f16* kthi  = ws + 2 * PL;      // packed K frags [H][B][16][4][2][64][8]
    f16* ktlo  = ws + 3 * PL;
    f16* vPck  = ws + 4 * PL;      // packed V frags [H][64][2][4][64][8]
    f16* ctx   = ws + 5 * PL;      // [BT][512]
    f16* qAhi  = ws + 6 * PL;
    f16* qAlo  = ws + 7 * PL;
    f16* kvAhi = ws + 8 * PL;
    f16* kvAlo = ws + 9 * PL;
    f16* wqh = ws + 10 * PL;
    f16* wql = wqh + 1 * WPL;
    f16* wkh = wqh + 2 * WPL;
    f16* wkl = wqh + 3 * WPL;
    f16* wvh = wqh + 4 * WPL;
    f16* woh = wqh + 5 * WPL;

    prep_k<<<dim3(1024, 6), dim3(256), 0, stream>>>(
        q, kv, Wq, Wk, Wv, Wo, wqh, wql, wkh, wkl, wvh, woh,
        qAhi, qAlo, kvAhi, kvAlo);

    proj_k<<<dim3(BT / 128, EE / 64, 2), dim3(256), 0, stream>>>(
        qAhi, qAlo, kvAhi, kvAlo, wqh, wql, wkh, wkl, wvh,
        qhi, qlo, kthi, ktlo, vPck);

    attn_mfma_k<<<dim3(256), dim3(512), 0, stream>>>(
        qhi, qlo, kthi, ktlo, vPck, ctx);

    outmm_k<<<dim3(BT / 64, EE / 64), dim3(256), 0, stream>>>(ctx, woh, out);
}